// Round 10
// baseline (727.989 us; speedup 1.0000x reference)
//
#include <hip/hip_runtime.h>
#include <hip/hip_bf16.h>
#include <math.h>

// ---------------------------------------------------------------------------
// GCN GraphRegressor: 3x (linear -> gather*norm -> scatter-sum -> relu)
//                     -> segment-mean pool -> MLP head
// R10: factorized GCN norm: 1/sqrt(deg_s*deg_d) = rsq[s]*rsq[d].
//   - GEMM epilogues scale rows by rsq[row]; aggregate applies rsq[node] once.
//   - Edge metadata = csrc only (4B/edge); fill_all loses 1.6M random
//     indeg[s] reads; aggregate inner loop = pure vector adds (no norm).
//   - uber0 = count_deg || wsplit || graph_bounds || pool-zero;
//     uber1 = fill_all || gemm1 (independent, overlapped).
// Floors (measured): gather FETCH 402MB = 100K rows x 512B x 8 XCD compulsory
// per-XCD fill at ~3.9 TB/s random-line fabric BW -> ~105us/aggregate.
// ---------------------------------------------------------------------------

typedef float f32x4 __attribute__((ext_vector_type(4)));
typedef short s16x8 __attribute__((ext_vector_type(8)));

__device__ __forceinline__ unsigned short f2bf(float x) {
  unsigned u = __float_as_uint(x);
  unsigned r = (u + 0x7FFFu + ((u >> 16) & 1u)) >> 16;
  return (unsigned short)r;
}

// ---- per-tile (1024) sums of indeg+1 --------------------------------------
__global__ __launch_bounds__(1024) void tile_reduce_kernel(
    const int* __restrict__ indeg, int* __restrict__ tilesum, int n) {
  __shared__ int ws[16];
  int i = blockIdx.x * 1024 + threadIdx.x;
  int v = (i < n) ? (indeg[i] + 1) : 0;
  for (int off = 32; off > 0; off >>= 1) v += __shfl_down(v, off);
  int wid = threadIdx.x >> 6, lane = threadIdx.x & 63;
  if (lane == 0) ws[wid] = v;
  __syncthreads();
  if (threadIdx.x == 0) {
    int s = 0;
    for (int w = 0; w < 16; ++w) s += ws[w];
    tilesum[blockIdx.x] = s;
  }
}

// ---- per-tile scan + tile prefix; writes ptr, cursor(=ptr), rsq -----------
__global__ __launch_bounds__(1024) void scan_emit_kernel(
    const int* __restrict__ indeg, const int* __restrict__ tilesum,
    int* __restrict__ ptr, int* __restrict__ cursor, float* __restrict__ rsq,
    int n, int T) {
  __shared__ int wsum[16];
  __shared__ int tilebase_s;
  int bid = blockIdx.x;
  int lane = threadIdx.x & 63, wid = threadIdx.x >> 6;
  if (threadIdx.x < 64) {
    int acc = 0;
    for (int t = threadIdx.x; t < bid; t += 64) acc += tilesum[t];
    for (int off = 32; off > 0; off >>= 1) acc += __shfl_down(acc, off);
    if (threadIdx.x == 0) tilebase_s = acc;
  }
  __syncthreads();
  int tilebase = tilebase_s;
  int i = bid * 1024 + threadIdx.x;
  int v = (i < n) ? (indeg[i] + 1) : 0;
  int x = v;
  for (int off = 1; off < 64; off <<= 1) {
    int y = __shfl_up(x, off);
    if (lane >= off) x += y;
  }
  if (lane == 63) wsum[wid] = x;
  __syncthreads();
  if (threadIdx.x == 0) {
    int run = 0;
    for (int w = 0; w < 16; ++w) { int t = wsum[w]; wsum[w] = run; run += t; }
  }
  __syncthreads();
  if (i < n) {
    int p = x - v + wsum[wid] + tilebase;
    ptr[i] = p;
    cursor[i] = p;
    rsq[i] = 1.0f / sqrtf((float)v);
  }
  if (bid == T - 1 && threadIdx.x == 1023) ptr[n] = tilebase + wsum[15] + x;
}

// ---- W split into bf16 hi/lo MFMA B-fragment layout (device body) ---------
__device__ __forceinline__ void wsplit_body(
    int blk, const float* __restrict__ W0, const float* __restrict__ W1,
    const float* __restrict__ W2, short* __restrict__ Whi, short* __restrict__ Wlo) {
  int layer = blk >> 6;
  int i = (blk & 63) * 256 + threadIdx.x;
  const float* W = (layer == 0) ? W0 : (layer == 1) ? W1 : W2;
  int j = i & 7, lane = (i >> 3) & 63, ks = (i >> 9) & 3, nt = i >> 11;
  int k = ks * 32 + (lane >> 4) * 8 + j;
  int nn = nt * 16 + (lane & 15);
  float w = W[k * 128 + nn];
  unsigned short h = f2bf(w);
  float hf = __uint_as_float(((unsigned)h) << 16);
  Whi[layer * 16384 + i] = (short)h;
  Wlo[layer * 16384 + i] = (short)f2bf(w - hf);
}

// uber0: [count_deg | wsplit(192) | graph_bounds | pool-zero]
__global__ __launch_bounds__(256) void uber0_kernel(
    const int* __restrict__ dst, int* __restrict__ indeg, int E,
    const float* __restrict__ W0, const float* __restrict__ W1,
    const float* __restrict__ W2, short* __restrict__ Whi, short* __restrict__ Wlo,
    const int* __restrict__ batch, int* __restrict__ gptr, int n, int G,
    float* __restrict__ pool, int CD, int GBD) {
  int b = blockIdx.x;
  if (b < CD) {
    int e = b * 256 + threadIdx.x;
    if (e < E) atomicAdd(&indeg[dst[e]], 1);
  } else if (b < CD + 192) {
    wsplit_body(b - CD, W0, W1, W2, Whi, Wlo);
  } else if (b < CD + 192 + GBD) {
    int i = (b - CD - 192) * 256 + threadIdx.x;
    if (i < n) {
      int bb = batch[i];
      if (i == 0) {
        for (int g = 0; g <= bb; ++g) gptr[g] = 0;
      } else {
        int bp = batch[i - 1];
        for (int g = bp + 1; g <= bb; ++g) gptr[g] = i;
      }
      if (i == n - 1) {
        for (int g = bb + 1; g <= G; ++g) gptr[g] = n;
      }
    }
  } else {
    int i = (b - CD - 192 - GBD) * 256 + threadIdx.x;
    if (i * 4 < G * 128) ((float4*)pool)[i] = make_float4(0.f, 0.f, 0.f, 0.f);
  }
}

// gemm1 body: H[n,128] = (X @ W + b) * rsq[row] via 3x bf16-split MFMA
__device__ __forceinline__ void gemm1_body(
    int blk, const float* __restrict__ X, const short* __restrict__ Whi,
    const short* __restrict__ Wlo, const float* __restrict__ bias,
    const float* __restrict__ rsq, float* __restrict__ H, int n) {
  int wave = threadIdx.x >> 6, lane = threadIdx.x & 63;
  int quad = lane >> 4, m = lane & 15;
  int mbase = blk * 64 + wave * 16;
  int row = min(mbase + m, n - 1);
  const float* xr = X + (size_t)row * 128 + quad * 8;
  const s16x8* WH = (const s16x8*)Whi;
  const s16x8* WL = (const s16x8*)Wlo;
  f32x4 acc[8];
#pragma unroll
  for (int nt = 0; nt < 8; ++nt) acc[nt] = 0.f;
#pragma unroll
  for (int ks = 0; ks < 4; ++ks) {
    float4 xa = *(const float4*)(xr + ks * 32);
    float4 xb = *(const float4*)(xr + ks * 32 + 4);
    float xs[8] = {xa.x, xa.y, xa.z, xa.w, xb.x, xb.y, xb.z, xb.w};
    s16x8 ah, al;
#pragma unroll
    for (int j = 0; j < 8; ++j) {
      unsigned short h = f2bf(xs[j]);
      float hf = __uint_as_float(((unsigned)h) << 16);
      ah[j] = (short)h;
      al[j] = (short)f2bf(xs[j] - hf);
    }
#pragma unroll
    for (int nt = 0; nt < 8; ++nt) {
      s16x8 wh = WH[(nt * 4 + ks) * 64 + lane];
      s16x8 wl = WL[(nt * 4 + ks) * 64 + lane];
      acc[nt] = __builtin_amdgcn_mfma_f32_16x16x32_bf16(ah, wh, acc[nt], 0, 0, 0);
      acc[nt] = __builtin_amdgcn_mfma_f32_16x16x32_bf16(al, wh, acc[nt], 0, 0, 0);
      acc[nt] = __builtin_amdgcn_mfma_f32_16x16x32_bf16(ah, wl, acc[nt], 0, 0, 0);
    }
  }
  float rs[4];
#pragma unroll
  for (int r = 0; r < 4; ++r) {
    int rr = mbase + quad * 4 + r;
    rs[r] = (rr < n) ? rsq[rr] : 0.f;
  }
#pragma unroll
  for (int nt = 0; nt < 8; ++nt) {
    int col = nt * 16 + m;
    float b = bias[col];
#pragma unroll
    for (int r = 0; r < 4; ++r) {
      int rr = mbase + quad * 4 + r;
      if (rr < n) H[(size_t)rr * 128 + col] = (acc[nt][r] + b) * rs[r];
    }
  }
}

// uber1: [fill_all | gemm1] — both depend only on scan_emit outputs
__global__ __launch_bounds__(256) void uber1_kernel(
    const int* __restrict__ src, const int* __restrict__ dst,
    int* __restrict__ cursor, int* __restrict__ csrc, int E, int n,
    const float* __restrict__ x, const short* __restrict__ Whi,
    const short* __restrict__ Wlo, const float* __restrict__ b0,
    const float* __restrict__ rsq, float* __restrict__ bufA, int FA) {
  int b = blockIdx.x;
  if (b < FA) {
    int i = b * 256 + threadIdx.x;
    if (i < E) {
      int s = src[i], d = dst[i];
      int pos = atomicAdd(&cursor[d], 1);
      csrc[pos] = s;
    } else if (i < E + n) {
      int v = i - E;
      int pos = atomicAdd(&cursor[v], 1);
      csrc[pos] = v;
    }
  } else {
    gemm1_body(b - FA, x, Whi, Wlo, b0, rsq, bufA, n);
  }
}

// Aggregate core: half-wave sums one node's gathered rows (no per-edge norm).
// Guarded 8-deep unroll: up to 16 independent float4 gathers in flight/wave.
__device__ __forceinline__ f32x4 agg_sum(
    const f32x4* __restrict__ Hc, const int* __restrict__ ptr,
    const int* __restrict__ csrc, int node, int hl) {
  int beg = ptr[node], end = ptr[node + 1];
  f32x4 a0 = 0.f, a1 = 0.f, a2 = 0.f, a3 = 0.f;
  f32x4 a4 = 0.f, a5 = 0.f, a6 = 0.f, a7 = 0.f;
  for (int base = beg; base < end; base += 32) {
    int m = end - base;
    if (m > 32) m = 32;
    int sl = (hl < m) ? csrc[base + hl] : 0;
    int j = 0;
    for (; j + 7 < m; j += 8) {
      int s0 = __shfl(sl, j + 0, 32), s1 = __shfl(sl, j + 1, 32);
      int s2 = __shfl(sl, j + 2, 32), s3 = __shfl(sl, j + 3, 32);
      int s4 = __shfl(sl, j + 4, 32), s5 = __shfl(sl, j + 5, 32);
      int s6 = __shfl(sl, j + 6, 32), s7 = __shfl(sl, j + 7, 32);
      f32x4 h0 = Hc[(size_t)s0 * 32];
      f32x4 h1 = Hc[(size_t)s1 * 32];
      f32x4 h2 = Hc[(size_t)s2 * 32];
      f32x4 h3 = Hc[(size_t)s3 * 32];
      f32x4 h4 = Hc[(size_t)s4 * 32];
      f32x4 h5 = Hc[(size_t)s5 * 32];
      f32x4 h6 = Hc[(size_t)s6 * 32];
      f32x4 h7 = Hc[(size_t)s7 * 32];
      a0 += h0; a1 += h1; a2 += h2; a3 += h3;
      a4 += h4; a5 += h5; a6 += h6; a7 += h7;
    }
    for (; j + 3 < m; j += 4) {
      int s0 = __shfl(sl, j + 0, 32), s1 = __shfl(sl, j + 1, 32);
      int s2 = __shfl(sl, j + 2, 32), s3 = __shfl(sl, j + 3, 32);
      f32x4 h0 = Hc[(size_t)s0 * 32];
      f32x4 h1 = Hc[(size_t)s1 * 32];
      f32x4 h2 = Hc[(size_t)s2 * 32];
      f32x4 h3 = Hc[(size_t)s3 * 32];
      a0 += h0; a1 += h1; a2 += h2; a3 += h3;
    }
    for (; j < m; ++j) {
      int s0 = __shfl(sl, j, 32);
      a0 += Hc[(size_t)s0 * 32];
    }
  }
  return ((a0 + a1) + (a2 + a3)) + ((a4 + a5) + (a6 + a7));
}

// FUSED aggregate + next-layer GEMM (layers 2 and 3); epilogue scales by rsq.
#define LDS_STRIDE 132
__global__ __launch_bounds__(256) void agg_gemm_kernel(
    const float* __restrict__ H, const int* __restrict__ ptr,
    const int* __restrict__ csrc, const float* __restrict__ rsq,
    const short* __restrict__ Whi, const short* __restrict__ Wlo,
    const float* __restrict__ bias, float* __restrict__ Hout, int n) {
  __shared__ int lds[16 * LDS_STRIDE];
  int hw = threadIdx.x >> 5, hl = threadIdx.x & 31;
  int nbase = blockIdx.x * 16;
  const f32x4* Hc = (const f32x4*)(H + hl * 4);
#pragma unroll
  for (int rep = 0; rep < 2; ++rep) {
    int nl = hw + rep * 8;
    int node = nbase + nl;
    f32x4 o = 0.f;
    if (node < n) {
      f32x4 s = agg_sum(Hc, ptr, csrc, node, hl);
      float r = rsq[node];
      o.x = fmaxf(s.x * r, 0.f);
      o.y = fmaxf(s.y * r, 0.f);
      o.z = fmaxf(s.z * r, 0.f);
      o.w = fmaxf(s.w * r, 0.f);
    }
    int* dst = lds + nl * LDS_STRIDE + hl * 4;
#pragma unroll
    for (int c = 0; c < 4; ++c) {
      float v = o[c];
      unsigned short h = f2bf(v);
      float hf = __uint_as_float(((unsigned)h) << 16);
      unsigned short l = f2bf(v - hf);
      dst[c] = (int)((((unsigned)h) << 16) | l);
    }
  }
  __syncthreads();

  int wave = threadIdx.x >> 6, lane = threadIdx.x & 63;
  int quad = lane >> 4, m = lane & 15;
  const s16x8* WH = (const s16x8*)Whi;
  const s16x8* WL = (const s16x8*)Wlo;
  f32x4 acc0 = 0.f, acc1 = 0.f;
  int nt0 = wave * 2, nt1 = wave * 2 + 1;
#pragma unroll
  for (int ks = 0; ks < 4; ++ks) {
    const int* arow = lds + m * LDS_STRIDE + ks * 32 + quad * 8;
    s16x8 ah, al;
#pragma unroll
    for (int j = 0; j < 8; ++j) {
      unsigned p = (unsigned)arow[j];
      ah[j] = (short)(p >> 16);
      al[j] = (short)(p & 0xffffu);
    }
    s16x8 wh0 = WH[(nt0 * 4 + ks) * 64 + lane];
    s16x8 wl0 = WL[(nt0 * 4 + ks) * 64 + lane];
    s16x8 wh1 = WH[(nt1 * 4 + ks) * 64 + lane];
    s16x8 wl1 = WL[(nt1 * 4 + ks) * 64 + lane];
    acc0 = __builtin_amdgcn_mfma_f32_16x16x32_bf16(ah, wh0, acc0, 0, 0, 0);
    acc0 = __builtin_amdgcn_mfma_f32_16x16x32_bf16(al, wh0, acc0, 0, 0, 0);
    acc0 = __builtin_amdgcn_mfma_f32_16x16x32_bf16(ah, wl0, acc0, 0, 0, 0);
    acc1 = __builtin_amdgcn_mfma_f32_16x16x32_bf16(ah, wh1, acc1, 0, 0, 0);
    acc1 = __builtin_amdgcn_mfma_f32_16x16x32_bf16(al, wh1, acc1, 0, 0, 0);
    acc1 = __builtin_amdgcn_mfma_f32_16x16x32_bf16(ah, wl1, acc1, 0, 0, 0);
  }
  float rs[4];
#pragma unroll
  for (int r = 0; r < 4; ++r) {
    int rr = nbase + quad * 4 + r;
    rs[r] = (rr < n) ? rsq[rr] : 0.f;
  }
#pragma unroll
  for (int t = 0; t < 2; ++t) {
    int nt = wave * 2 + t;
    int col = nt * 16 + m;
    float b = bias[col];
    f32x4 a = t ? acc1 : acc0;
#pragma unroll
    for (int r = 0; r < 4; ++r) {
      int rr = nbase + quad * 4 + r;
      if (rr < n) Hout[(size_t)rr * 128 + col] = (a[r] + b) * rs[r];
    }
  }
}

// FUSED layer-3 aggregate + segment-sum pool (block per-graph partials).
__global__ __launch_bounds__(256) void agg_pool_kernel(
    const float* __restrict__ H, const int* __restrict__ ptr,
    const int* __restrict__ csrc, const float* __restrict__ rsq,
    const int* __restrict__ batch, float* __restrict__ pool, int n) {
  __shared__ float rows[16][128];
  __shared__ int gids[16];
  int hw = threadIdx.x >> 5, hl = threadIdx.x & 31;
  int nbase = blockIdx.x * 16;
  const f32x4* Hc = (const f32x4*)(H + hl * 4);
#pragma unroll
  for (int rep = 0; rep < 2; ++rep) {
    int nl = hw + rep * 8;
    int node = nbase + nl;
    f32x4 o = 0.f;
    if (node < n) {
      f32x4 s = agg_sum(Hc, ptr, csrc, node, hl);
      float r = rsq[node];
      o.x = fmaxf(s.x * r, 0.f);
      o.y = fmaxf(s.y * r, 0.f);
      o.z = fmaxf(s.z * r, 0.f);
      o.w = fmaxf(s.w * r, 0.f);
    }
    *(f32x4*)&rows[nl][hl * 4] = o;
    if (hl == 0) gids[nl] = (node < n) ? batch[node] : -1;
  }
  __syncthreads();
  int half = threadIdx.x >> 7;
  int ch = threadIdx.x & 127;
  float acc = 0.f;
  int curg = gids[half * 8];
  for (int i = half * 8; i < half * 8 + 8; ++i) {
    int g = gids[i];
    if (g != curg) {
      if (curg >= 0) atomicAdd(&pool[(size_t)curg * 128 + ch], acc);
      acc = 0.f;
      curg = g;
    }
    if (g >= 0) acc += rows[i][ch];
  }
  if (curg >= 0) atomicAdd(&pool[(size_t)curg * 128 + ch], acc);
}

// MLP head per graph: mean = pool/cnt (cnt from gptr), 2-layer MLP.
__global__ __launch_bounds__(128) void head_kernel(
    const float* __restrict__ pool, const int* __restrict__ gptr,
    const float* __restrict__ Wp1, const float* __restrict__ bp1,
    const float* __restrict__ Wp2, const float* __restrict__ bp2,
    float* __restrict__ out, int G) {
  int g = blockIdx.x;
  int j = threadIdx.x;
  __shared__ float ps[128];
  __shared__ float hs[128];
  int cnt = gptr[g + 1] - gptr[g];
  float inv = 1.0f / (float)max(cnt, 1);
  ps[j] = pool[(size_t)g * 128 + j] * inv;
  __syncthreads();
  float acc = bp1[j];
#pragma unroll 8
  for (int k = 0; k < 128; ++k) acc = fmaf(ps[k], Wp1[k * 128 + j], acc);
  hs[j] = fmaxf(acc, 0.f) * Wp2[j];
  __syncthreads();
  for (int off = 64; off > 0; off >>= 1) {
    if (j < off) hs[j] += hs[j + off];
    __syncthreads();
  }
  if (j == 0) out[g] = hs[0] + bp2[0];
}

extern "C" void kernel_launch(void* const* d_in, const int* in_sizes, int n_in,
                              void* d_out, int out_size, void* d_ws, size_t ws_size,
                              hipStream_t stream) {
  const float* x    = (const float*)d_in[0];
  const int*   eidx = (const int*)d_in[1];
  const int*   batch= (const int*)d_in[2];
  const float* W0 = (const float*)d_in[3];
  const float* b0 = (const float*)d_in[4];
  const float* W1 = (const float*)d_in[5];
  const float* b1 = (const float*)d_in[6];
  const float* W2 = (const float*)d_in[7];
  const float* b2 = (const float*)d_in[8];
  const float* Wp1 = (const float*)d_in[9];
  const float* bp1 = (const float*)d_in[10];
  const float* Wp2 = (const float*)d_in[11];
  const float* bp2 = (const float*)d_in[12];
  float* out = (float*)d_out;

  const int N = in_sizes[0] / 128;
  const int E = in_sizes[1] / 2;
  const int G = out_size;
  const int M = E + N;
  const int T = (N + 1023) / 1024;

  const int* src = eidx;
  const int* dst = eidx + E;

  char* ws = (char*)d_ws;
  size_t off = 0;
  auto alloc = [&](size_t bytes) -> void* {
    void* p = ws + off;
    off = (off + bytes + 255) & ~(size_t)255;
    return p;
  };
  int*   indeg   = (int*)  alloc((size_t)N * 4);
  int*   cursor  = (int*)  alloc((size_t)N * 4);
  int*   ptr     = (int*)  alloc((size_t)(N + 1) * 4);
  float* rsq     = (float*)alloc((size_t)N * 4);
  int*   csrc    = (int*)  alloc((size_t)M * 4);
  float* bufA    = (float*)alloc((size_t)N * 128 * 4);
  float* bufB    = (float*)alloc((size_t)N * 128 * 4);
  int*   gptr    = (int*)  alloc((size_t)(G + 1) * 4);
  float* pool    = (float*)alloc((size_t)G * 128 * 4);
  int*   tilesum = (int*)  alloc((size_t)T * 4);
  short* whi     = (short*)alloc(3 * 16384 * 2);
  short* wlo     = (short*)alloc(3 * 16384 * 2);
  (void)ws_size;

  hipMemsetAsync(indeg, 0, (size_t)N * 4, stream);

  const int CD  = (E + 255) / 256;
  const int GBD = (N + 255) / 256;
  const int PZ  = (G * 128 / 4 + 255) / 256;
  uber0_kernel<<<CD + 192 + GBD + PZ, 256, 0, stream>>>(
      dst, indeg, E, W0, W1, W2, whi, wlo, batch, gptr, N, G, pool, CD, GBD);

  tile_reduce_kernel<<<T, 1024, 0, stream>>>(indeg, tilesum, N);
  scan_emit_kernel<<<T, 1024, 0, stream>>>(indeg, tilesum, ptr, cursor, rsq, N, T);

  const int FA = (E + N + 255) / 256;
  const int GB = (N + 63) / 64;
  uber1_kernel<<<FA + GB, 256, 0, stream>>>(
      src, dst, cursor, csrc, E, N, x, whi, wlo, b0, rsq, bufA, FA);

  dim3 fused_grid((N + 15) / 16);
  agg_gemm_kernel<<<fused_grid, 256, 0, stream>>>(bufA, ptr, csrc, rsq,
      whi + 16384, wlo + 16384, b1, bufB, N);
  agg_gemm_kernel<<<fused_grid, 256, 0, stream>>>(bufB, ptr, csrc, rsq,
      whi + 2 * 16384, wlo + 2 * 16384, b2, bufA, N);
  agg_pool_kernel<<<fused_grid, 256, 0, stream>>>(bufA, ptr, csrc, rsq, batch, pool, N);

  head_kernel<<<G, 128, 0, stream>>>(pool, gptr, Wp1, bp1, Wp2, bp2, out, G);
}

// Round 11
// 708.762 us; speedup vs baseline: 1.0271x; 1.0271x over previous
//
#include <hip/hip_runtime.h>
#include <hip/hip_bf16.h>
#include <math.h>

// ---------------------------------------------------------------------------
// GCN GraphRegressor: 3x (linear -> gather*norm -> scatter-sum -> relu)
//                     -> segment-mean pool -> MLP head
// R11: R10's factorized norm kept (rsq in GEMM epilogue, adds-only gather),
//   but fill_all is a LEAN STANDALONE kernel again (R10 lesson: fusing the
//   atomic-latency-bound fill with register-heavy gemm killed its occupancy).
//   Self-loops removed from CSR: aggregate adds own row directly (norm =
//   rsq[i]^2 falls out of the factorization). CSR = E edges only.
// Floors (measured): gather FETCH 402MB = compulsory per-XCD fill, ~3.9TB/s
// random-line fabric BW; fill is bound by returned-atomic throughput.
// ---------------------------------------------------------------------------

typedef float f32x4 __attribute__((ext_vector_type(4)));
typedef short s16x8 __attribute__((ext_vector_type(8)));

__device__ __forceinline__ unsigned short f2bf(float x) {
  unsigned u = __float_as_uint(x);
  unsigned r = (u + 0x7FFFu + ((u >> 16) & 1u)) >> 16;
  return (unsigned short)r;
}

// ---- per-tile (1024) sums of indeg ----------------------------------------
__global__ __launch_bounds__(1024) void tile_reduce_kernel(
    const int* __restrict__ indeg, int* __restrict__ tilesum, int n) {
  __shared__ int ws[16];
  int i = blockIdx.x * 1024 + threadIdx.x;
  int v = (i < n) ? indeg[i] : 0;
  for (int off = 32; off > 0; off >>= 1) v += __shfl_down(v, off);
  int wid = threadIdx.x >> 6, lane = threadIdx.x & 63;
  if (lane == 0) ws[wid] = v;
  __syncthreads();
  if (threadIdx.x == 0) {
    int s = 0;
    for (int w = 0; w < 16; ++w) s += ws[w];
    tilesum[blockIdx.x] = s;
  }
}

// ---- per-tile scan + tile prefix; writes ptr, cursor(=ptr), rsq -----------
__global__ __launch_bounds__(1024) void scan_emit_kernel(
    const int* __restrict__ indeg, const int* __restrict__ tilesum,
    int* __restrict__ ptr, int* __restrict__ cursor, float* __restrict__ rsq,
    int n, int T) {
  __shared__ int wsum[16];
  __shared__ int tilebase_s;
  int bid = blockIdx.x;
  int lane = threadIdx.x & 63, wid = threadIdx.x >> 6;
  if (threadIdx.x < 64) {
    int acc = 0;
    for (int t = threadIdx.x; t < bid; t += 64) acc += tilesum[t];
    for (int off = 32; off > 0; off >>= 1) acc += __shfl_down(acc, off);
    if (threadIdx.x == 0) tilebase_s = acc;
  }
  __syncthreads();
  int tilebase = tilebase_s;
  int i = bid * 1024 + threadIdx.x;
  int v = (i < n) ? indeg[i] : 0;
  int x = v;
  for (int off = 1; off < 64; off <<= 1) {
    int y = __shfl_up(x, off);
    if (lane >= off) x += y;
  }
  if (lane == 63) wsum[wid] = x;
  __syncthreads();
  if (threadIdx.x == 0) {
    int run = 0;
    for (int w = 0; w < 16; ++w) { int t = wsum[w]; wsum[w] = run; run += t; }
  }
  __syncthreads();
  if (i < n) {
    int p = x - v + wsum[wid] + tilebase;
    ptr[i] = p;
    cursor[i] = p;
    rsq[i] = 1.0f / sqrtf((float)(v + 1));  // degree incl. self-loop
  }
  if (bid == T - 1 && threadIdx.x == 1023) ptr[n] = tilebase + wsum[15] + x;
}

// ---- W split into bf16 hi/lo MFMA B-fragment layout (device body) ---------
__device__ __forceinline__ void wsplit_body(
    int blk, const float* __restrict__ W0, const float* __restrict__ W1,
    const float* __restrict__ W2, short* __restrict__ Whi, short* __restrict__ Wlo) {
  int layer = blk >> 6;
  int i = (blk & 63) * 256 + threadIdx.x;
  const float* W = (layer == 0) ? W0 : (layer == 1) ? W1 : W2;
  int j = i & 7, lane = (i >> 3) & 63, ks = (i >> 9) & 3, nt = i >> 11;
  int k = ks * 32 + (lane >> 4) * 8 + j;
  int nn = nt * 16 + (lane & 15);
  float w = W[k * 128 + nn];
  unsigned short h = f2bf(w);
  float hf = __uint_as_float(((unsigned)h) << 16);
  Whi[layer * 16384 + i] = (short)h;
  Wlo[layer * 16384 + i] = (short)f2bf(w - hf);
}

// uber0: [count_deg | wsplit(192) | graph_bounds | pool-zero]
__global__ __launch_bounds__(256) void uber0_kernel(
    const int* __restrict__ dst, int* __restrict__ indeg, int E,
    const float* __restrict__ W0, const float* __restrict__ W1,
    const float* __restrict__ W2, short* __restrict__ Whi, short* __restrict__ Wlo,
    const int* __restrict__ batch, int* __restrict__ gptr, int n, int G,
    float* __restrict__ pool, int CD, int GBD) {
  int b = blockIdx.x;
  if (b < CD) {
    int e = b * 256 + threadIdx.x;
    if (e < E) atomicAdd(&indeg[dst[e]], 1);
  } else if (b < CD + 192) {
    wsplit_body(b - CD, W0, W1, W2, Whi, Wlo);
  } else if (b < CD + 192 + GBD) {
    int i = (b - CD - 192) * 256 + threadIdx.x;
    if (i < n) {
      int bb = batch[i];
      if (i == 0) {
        for (int g = 0; g <= bb; ++g) gptr[g] = 0;
      } else {
        int bp = batch[i - 1];
        for (int g = bp + 1; g <= bb; ++g) gptr[g] = i;
      }
      if (i == n - 1) {
        for (int g = bb + 1; g <= G; ++g) gptr[g] = n;
      }
    }
  } else {
    int i = (b - CD - 192 - GBD) * 256 + threadIdx.x;
    if (i * 4 < G * 128) ((float4*)pool)[i] = make_float4(0.f, 0.f, 0.f, 0.f);
  }
}

// lean standalone CSR fill: edges only (no self-loops), cursor pre-set to ptr
__global__ void fill_all_kernel(const int* __restrict__ src, const int* __restrict__ dst,
                                int* __restrict__ cursor, int* __restrict__ csrc, int E) {
  int i = blockIdx.x * 256 + threadIdx.x;
  if (i < E) {
    int s = src[i], d = dst[i];
    int pos = atomicAdd(&cursor[d], 1);
    csrc[pos] = s;
  }
}

// gemm1: H[n,128] = (X @ W + b) * rsq[row] via 3x bf16-split MFMA
__global__ __launch_bounds__(256) void gemm1_kernel(
    const float* __restrict__ X, const short* __restrict__ Whi,
    const short* __restrict__ Wlo, const float* __restrict__ bias,
    const float* __restrict__ rsq, float* __restrict__ H, int n) {
  int wave = threadIdx.x >> 6, lane = threadIdx.x & 63;
  int quad = lane >> 4, m = lane & 15;
  int mbase = blockIdx.x * 64 + wave * 16;
  int row = min(mbase + m, n - 1);
  const float* xr = X + (size_t)row * 128 + quad * 8;
  const s16x8* WH = (const s16x8*)Whi;
  const s16x8* WL = (const s16x8*)Wlo;
  f32x4 acc[8];
#pragma unroll
  for (int nt = 0; nt < 8; ++nt) acc[nt] = 0.f;
#pragma unroll
  for (int ks = 0; ks < 4; ++ks) {
    float4 xa = *(const float4*)(xr + ks * 32);
    float4 xb = *(const float4*)(xr + ks * 32 + 4);
    float xs[8] = {xa.x, xa.y, xa.z, xa.w, xb.x, xb.y, xb.z, xb.w};
    s16x8 ah, al;
#pragma unroll
    for (int j = 0; j < 8; ++j) {
      unsigned short h = f2bf(xs[j]);
      float hf = __uint_as_float(((unsigned)h) << 16);
      ah[j] = (short)h;
      al[j] = (short)f2bf(xs[j] - hf);
    }
#pragma unroll
    for (int nt = 0; nt < 8; ++nt) {
      s16x8 wh = WH[(nt * 4 + ks) * 64 + lane];
      s16x8 wl = WL[(nt * 4 + ks) * 64 + lane];
      acc[nt] = __builtin_amdgcn_mfma_f32_16x16x32_bf16(ah, wh, acc[nt], 0, 0, 0);
      acc[nt] = __builtin_amdgcn_mfma_f32_16x16x32_bf16(al, wh, acc[nt], 0, 0, 0);
      acc[nt] = __builtin_amdgcn_mfma_f32_16x16x32_bf16(ah, wl, acc[nt], 0, 0, 0);
    }
  }
  float rs[4];
#pragma unroll
  for (int r = 0; r < 4; ++r) {
    int rr = mbase + quad * 4 + r;
    rs[r] = (rr < n) ? rsq[rr] : 0.f;
  }
#pragma unroll
  for (int nt = 0; nt < 8; ++nt) {
    int col = nt * 16 + m;
    float b = bias[col];
#pragma unroll
    for (int r = 0; r < 4; ++r) {
      int rr = mbase + quad * 4 + r;
      if (rr < n) H[(size_t)rr * 128 + col] = (acc[nt][r] + b) * rs[r];
    }
  }
}

// Aggregate core: half-wave sums one node's gathered rows + own row (self).
// Guarded 8-deep unroll: up to 16 independent float4 gathers in flight/wave.
__device__ __forceinline__ f32x4 agg_sum(
    const f32x4* __restrict__ Hc, const int* __restrict__ ptr,
    const int* __restrict__ csrc, int node, int hl) {
  int beg = ptr[node], end = ptr[node + 1];
  f32x4 a0 = Hc[(size_t)node * 32];  // self-loop term (pre-scaled row)
  f32x4 a1 = 0.f, a2 = 0.f, a3 = 0.f;
  f32x4 a4 = 0.f, a5 = 0.f, a6 = 0.f, a7 = 0.f;
  for (int base = beg; base < end; base += 32) {
    int m = end - base;
    if (m > 32) m = 32;
    int sl = (hl < m) ? csrc[base + hl] : 0;
    int j = 0;
    for (; j + 7 < m; j += 8) {
      int s0 = __shfl(sl, j + 0, 32), s1 = __shfl(sl, j + 1, 32);
      int s2 = __shfl(sl, j + 2, 32), s3 = __shfl(sl, j + 3, 32);
      int s4 = __shfl(sl, j + 4, 32), s5 = __shfl(sl, j + 5, 32);
      int s6 = __shfl(sl, j + 6, 32), s7 = __shfl(sl, j + 7, 32);
      f32x4 h0 = Hc[(size_t)s0 * 32];
      f32x4 h1 = Hc[(size_t)s1 * 32];
      f32x4 h2 = Hc[(size_t)s2 * 32];
      f32x4 h3 = Hc[(size_t)s3 * 32];
      f32x4 h4 = Hc[(size_t)s4 * 32];
      f32x4 h5 = Hc[(size_t)s5 * 32];
      f32x4 h6 = Hc[(size_t)s6 * 32];
      f32x4 h7 = Hc[(size_t)s7 * 32];
      a0 += h0; a1 += h1; a2 += h2; a3 += h3;
      a4 += h4; a5 += h5; a6 += h6; a7 += h7;
    }
    for (; j + 3 < m; j += 4) {
      int s0 = __shfl(sl, j + 0, 32), s1 = __shfl(sl, j + 1, 32);
      int s2 = __shfl(sl, j + 2, 32), s3 = __shfl(sl, j + 3, 32);
      f32x4 h0 = Hc[(size_t)s0 * 32];
      f32x4 h1 = Hc[(size_t)s1 * 32];
      f32x4 h2 = Hc[(size_t)s2 * 32];
      f32x4 h3 = Hc[(size_t)s3 * 32];
      a0 += h0; a1 += h1; a2 += h2; a3 += h3;
    }
    for (; j < m; ++j) {
      int s0 = __shfl(sl, j, 32);
      a0 += Hc[(size_t)s0 * 32];
    }
  }
  return ((a0 + a1) + (a2 + a3)) + ((a4 + a5) + (a6 + a7));
}

// FUSED aggregate + next-layer GEMM (layers 2 and 3); epilogue scales by rsq.
#define LDS_STRIDE 132
__global__ __launch_bounds__(256) void agg_gemm_kernel(
    const float* __restrict__ H, const int* __restrict__ ptr,
    const int* __restrict__ csrc, const float* __restrict__ rsq,
    const short* __restrict__ Whi, const short* __restrict__ Wlo,
    const float* __restrict__ bias, float* __restrict__ Hout, int n) {
  __shared__ int lds[16 * LDS_STRIDE];
  int hw = threadIdx.x >> 5, hl = threadIdx.x & 31;
  int nbase = blockIdx.x * 16;
  const f32x4* Hc = (const f32x4*)(H + hl * 4);
#pragma unroll
  for (int rep = 0; rep < 2; ++rep) {
    int nl = hw + rep * 8;
    int node = nbase + nl;
    f32x4 o = 0.f;
    if (node < n) {
      f32x4 s = agg_sum(Hc, ptr, csrc, node, hl);
      float r = rsq[node];
      o.x = fmaxf(s.x * r, 0.f);
      o.y = fmaxf(s.y * r, 0.f);
      o.z = fmaxf(s.z * r, 0.f);
      o.w = fmaxf(s.w * r, 0.f);
    }
    int* dst = lds + nl * LDS_STRIDE + hl * 4;
#pragma unroll
    for (int c = 0; c < 4; ++c) {
      float v = o[c];
      unsigned short h = f2bf(v);
      float hf = __uint_as_float(((unsigned)h) << 16);
      unsigned short l = f2bf(v - hf);
      dst[c] = (int)((((unsigned)h) << 16) | l);
    }
  }
  __syncthreads();

  int wave = threadIdx.x >> 6, lane = threadIdx.x & 63;
  int quad = lane >> 4, m = lane & 15;
  const s16x8* WH = (const s16x8*)Whi;
  const s16x8* WL = (const s16x8*)Wlo;
  f32x4 acc0 = 0.f, acc1 = 0.f;
  int nt0 = wave * 2, nt1 = wave * 2 + 1;
#pragma unroll
  for (int ks = 0; ks < 4; ++ks) {
    const int* arow = lds + m * LDS_STRIDE + ks * 32 + quad * 8;
    s16x8 ah, al;
#pragma unroll
    for (int j = 0; j < 8; ++j) {
      unsigned p = (unsigned)arow[j];
      ah[j] = (short)(p >> 16);
      al[j] = (short)(p & 0xffffu);
    }
    s16x8 wh0 = WH[(nt0 * 4 + ks) * 64 + lane];
    s16x8 wl0 = WL[(nt0 * 4 + ks) * 64 + lane];
    s16x8 wh1 = WH[(nt1 * 4 + ks) * 64 + lane];
    s16x8 wl1 = WL[(nt1 * 4 + ks) * 64 + lane];
    acc0 = __builtin_amdgcn_mfma_f32_16x16x32_bf16(ah, wh0, acc0, 0, 0, 0);
    acc0 = __builtin_amdgcn_mfma_f32_16x16x32_bf16(al, wh0, acc0, 0, 0, 0);
    acc0 = __builtin_amdgcn_mfma_f32_16x16x32_bf16(ah, wl0, acc0, 0, 0, 0);
    acc1 = __builtin_amdgcn_mfma_f32_16x16x32_bf16(ah, wh1, acc1, 0, 0, 0);
    acc1 = __builtin_amdgcn_mfma_f32_16x16x32_bf16(al, wh1, acc1, 0, 0, 0);
    acc1 = __builtin_amdgcn_mfma_f32_16x16x32_bf16(ah, wl1, acc1, 0, 0, 0);
  }
  float rs[4];
#pragma unroll
  for (int r = 0; r < 4; ++r) {
    int rr = nbase + quad * 4 + r;
    rs[r] = (rr < n) ? rsq[rr] : 0.f;
  }
#pragma unroll
  for (int t = 0; t < 2; ++t) {
    int nt = wave * 2 + t;
    int col = nt * 16 + m;
    float b = bias[col];
    f32x4 a = t ? acc1 : acc0;
#pragma unroll
    for (int r = 0; r < 4; ++r) {
      int rr = nbase + quad * 4 + r;
      if (rr < n) Hout[(size_t)rr * 128 + col] = (a[r] + b) * rs[r];
    }
  }
}

// FUSED layer-3 aggregate + segment-sum pool (block per-graph partials).
__global__ __launch_bounds__(256) void agg_pool_kernel(
    const float* __restrict__ H, const int* __restrict__ ptr,
    const int* __restrict__ csrc, const float* __restrict__ rsq,
    const int* __restrict__ batch, float* __restrict__ pool, int n) {
  __shared__ float rows[16][128];
  __shared__ int gids[16];
  int hw = threadIdx.x >> 5, hl = threadIdx.x & 31;
  int nbase = blockIdx.x * 16;
  const f32x4* Hc = (const f32x4*)(H + hl * 4);
#pragma unroll
  for (int rep = 0; rep < 2; ++rep) {
    int nl = hw + rep * 8;
    int node = nbase + nl;
    f32x4 o = 0.f;
    if (node < n) {
      f32x4 s = agg_sum(Hc, ptr, csrc, node, hl);
      float r = rsq[node];
      o.x = fmaxf(s.x * r, 0.f);
      o.y = fmaxf(s.y * r, 0.f);
      o.z = fmaxf(s.z * r, 0.f);
      o.w = fmaxf(s.w * r, 0.f);
    }
    *(f32x4*)&rows[nl][hl * 4] = o;
    if (hl == 0) gids[nl] = (node < n) ? batch[node] : -1;
  }
  __syncthreads();
  int half = threadIdx.x >> 7;
  int ch = threadIdx.x & 127;
  float acc = 0.f;
  int curg = gids[half * 8];
  for (int i = half * 8; i < half * 8 + 8; ++i) {
    int g = gids[i];
    if (g != curg) {
      if (curg >= 0) atomicAdd(&pool[(size_t)curg * 128 + ch], acc);
      acc = 0.f;
      curg = g;
    }
    if (g >= 0) acc += rows[i][ch];
  }
  if (curg >= 0) atomicAdd(&pool[(size_t)curg * 128 + ch], acc);
}

// MLP head per graph: mean = pool/cnt (cnt from gptr), 2-layer MLP.
__global__ __launch_bounds__(128) void head_kernel(
    const float* __restrict__ pool, const int* __restrict__ gptr,
    const float* __restrict__ Wp1, const float* __restrict__ bp1,
    const float* __restrict__ Wp2, const float* __restrict__ bp2,
    float* __restrict__ out, int G) {
  int g = blockIdx.x;
  int j = threadIdx.x;
  __shared__ float ps[128];
  __shared__ float hs[128];
  int cnt = gptr[g + 1] - gptr[g];
  float inv = 1.0f / (float)max(cnt, 1);
  ps[j] = pool[(size_t)g * 128 + j] * inv;
  __syncthreads();
  float acc = bp1[j];
#pragma unroll 8
  for (int k = 0; k < 128; ++k) acc = fmaf(ps[k], Wp1[k * 128 + j], acc);
  hs[j] = fmaxf(acc, 0.f) * Wp2[j];
  __syncthreads();
  for (int off = 64; off > 0; off >>= 1) {
    if (j < off) hs[j] += hs[j + off];
    __syncthreads();
  }
  if (j == 0) out[g] = hs[0] + bp2[0];
}

extern "C" void kernel_launch(void* const* d_in, const int* in_sizes, int n_in,
                              void* d_out, int out_size, void* d_ws, size_t ws_size,
                              hipStream_t stream) {
  const float* x    = (const float*)d_in[0];
  const int*   eidx = (const int*)d_in[1];
  const int*   batch= (const int*)d_in[2];
  const float* W0 = (const float*)d_in[3];
  const float* b0 = (const float*)d_in[4];
  const float* W1 = (const float*)d_in[5];
  const float* b1 = (const float*)d_in[6];
  const float* W2 = (const float*)d_in[7];
  const float* b2 = (const float*)d_in[8];
  const float* Wp1 = (const float*)d_in[9];
  const float* bp1 = (const float*)d_in[10];
  const float* Wp2 = (const float*)d_in[11];
  const float* bp2 = (const float*)d_in[12];
  float* out = (float*)d_out;

  const int N = in_sizes[0] / 128;
  const int E = in_sizes[1] / 2;
  const int G = out_size;
  const int T = (N + 1023) / 1024;

  const int* src = eidx;
  const int* dst = eidx + E;

  char* ws = (char*)d_ws;
  size_t off = 0;
  auto alloc = [&](size_t bytes) -> void* {
    void* p = ws + off;
    off = (off + bytes + 255) & ~(size_t)255;
    return p;
  };
  int*   indeg   = (int*)  alloc((size_t)N * 4);
  int*   cursor  = (int*)  alloc((size_t)N * 4);
  int*   ptr     = (int*)  alloc((size_t)(N + 1) * 4);
  float* rsq     = (float*)alloc((size_t)N * 4);
  int*   csrc    = (int*)  alloc((size_t)E * 4);
  float* bufA    = (float*)alloc((size_t)N * 128 * 4);
  float* bufB    = (float*)alloc((size_t)N * 128 * 4);
  int*   gptr    = (int*)  alloc((size_t)(G + 1) * 4);
  float* pool    = (float*)alloc((size_t)G * 128 * 4);
  int*   tilesum = (int*)  alloc((size_t)T * 4);
  short* whi     = (short*)alloc(3 * 16384 * 2);
  short* wlo     = (short*)alloc(3 * 16384 * 2);
  (void)ws_size;

  hipMemsetAsync(indeg, 0, (size_t)N * 4, stream);

  const int CD  = (E + 255) / 256;
  const int GBD = (N + 255) / 256;
  const int PZ  = (G * 128 / 4 + 255) / 256;
  uber0_kernel<<<CD + 192 + GBD + PZ, 256, 0, stream>>>(
      dst, indeg, E, W0, W1, W2, whi, wlo, batch, gptr, N, G, pool, CD, GBD);

  tile_reduce_kernel<<<T, 1024, 0, stream>>>(indeg, tilesum, N);
  scan_emit_kernel<<<T, 1024, 0, stream>>>(indeg, tilesum, ptr, cursor, rsq, N, T);

  fill_all_kernel<<<(E + 255) / 256, 256, 0, stream>>>(src, dst, cursor, csrc, E);
  gemm1_kernel<<<(N + 63) / 64, 256, 0, stream>>>(x, whi, wlo, b0, rsq, bufA, N);

  dim3 fused_grid((N + 15) / 16);
  agg_gemm_kernel<<<fused_grid, 256, 0, stream>>>(bufA, ptr, csrc, rsq,
      whi + 16384, wlo + 16384, b1, bufB, N);
  agg_gemm_kernel<<<fused_grid, 256, 0, stream>>>(bufB, ptr, csrc, rsq,
      whi + 2 * 16384, wlo + 2 * 16384, b2, bufA, N);
  agg_pool_kernel<<<fused_grid, 256, 0, stream>>>(bufA, ptr, csrc, rsq, batch, pool, N);

  head_kernel<<<G, 128, 0, stream>>>(pool, gptr, Wp1, bp1, Wp2, bp2, out, G);
}

// Round 12
// 616.930 us; speedup vs baseline: 1.1800x; 1.1489x over previous
//
#include <hip/hip_runtime.h>
#include <hip/hip_bf16.h>
#include <math.h>

// ---------------------------------------------------------------------------
// GCN GraphRegressor: 3x (linear -> gather*norm -> scatter-sum -> relu)
//                     -> segment-mean pool -> MLP head
// R12: rank trick — count_deg's atomicAdd RETURNS and stores rank[e]
//   (coalesced); fill becomes ATOMIC-FREE: csrc[ptr[d]+rank[e]] = src[e].
//   Contended-atomic serialization paid once (in uber0) instead of twice.
//   Keeps R11: factorized norm rsq, self-loop folded into aggregate,
//   adds-only gather loop, fused agg+gemm / agg+pool, bf16 3-split MFMA.
// Floors (measured): gather FETCH 402MB = compulsory per-XCD fill at
// ~3.9TB/s random-512B-line fabric BW -> ~120us/aggregate pass.
// ---------------------------------------------------------------------------

typedef float f32x4 __attribute__((ext_vector_type(4)));
typedef short s16x8 __attribute__((ext_vector_type(8)));

__device__ __forceinline__ unsigned short f2bf(float x) {
  unsigned u = __float_as_uint(x);
  unsigned r = (u + 0x7FFFu + ((u >> 16) & 1u)) >> 16;
  return (unsigned short)r;
}

// ---- per-tile (1024) sums of indeg ----------------------------------------
__global__ __launch_bounds__(1024) void tile_reduce_kernel(
    const int* __restrict__ indeg, int* __restrict__ tilesum, int n) {
  __shared__ int ws[16];
  int i = blockIdx.x * 1024 + threadIdx.x;
  int v = (i < n) ? indeg[i] : 0;
  for (int off = 32; off > 0; off >>= 1) v += __shfl_down(v, off);
  int wid = threadIdx.x >> 6, lane = threadIdx.x & 63;
  if (lane == 0) ws[wid] = v;
  __syncthreads();
  if (threadIdx.x == 0) {
    int s = 0;
    for (int w = 0; w < 16; ++w) s += ws[w];
    tilesum[blockIdx.x] = s;
  }
}

// ---- per-tile scan + tile prefix; writes ptr and rsq ----------------------
__global__ __launch_bounds__(1024) void scan_emit_kernel(
    const int* __restrict__ indeg, const int* __restrict__ tilesum,
    int* __restrict__ ptr, float* __restrict__ rsq, int n, int T) {
  __shared__ int wsum[16];
  __shared__ int tilebase_s;
  int bid = blockIdx.x;
  int lane = threadIdx.x & 63, wid = threadIdx.x >> 6;
  if (threadIdx.x < 64) {
    int acc = 0;
    for (int t = threadIdx.x; t < bid; t += 64) acc += tilesum[t];
    for (int off = 32; off > 0; off >>= 1) acc += __shfl_down(acc, off);
    if (threadIdx.x == 0) tilebase_s = acc;
  }
  __syncthreads();
  int tilebase = tilebase_s;
  int i = bid * 1024 + threadIdx.x;
  int v = (i < n) ? indeg[i] : 0;
  int x = v;
  for (int off = 1; off < 64; off <<= 1) {
    int y = __shfl_up(x, off);
    if (lane >= off) x += y;
  }
  if (lane == 63) wsum[wid] = x;
  __syncthreads();
  if (threadIdx.x == 0) {
    int run = 0;
    for (int w = 0; w < 16; ++w) { int t = wsum[w]; wsum[w] = run; run += t; }
  }
  __syncthreads();
  if (i < n) {
    ptr[i] = x - v + wsum[wid] + tilebase;
    rsq[i] = 1.0f / sqrtf((float)(v + 1));  // degree incl. self-loop
  }
  if (bid == T - 1 && threadIdx.x == 1023) ptr[n] = tilebase + wsum[15] + x;
}

// ---- W split into bf16 hi/lo MFMA B-fragment layout (device body) ---------
__device__ __forceinline__ void wsplit_body(
    int blk, const float* __restrict__ W0, const float* __restrict__ W1,
    const float* __restrict__ W2, short* __restrict__ Whi, short* __restrict__ Wlo) {
  int layer = blk >> 6;
  int i = (blk & 63) * 256 + threadIdx.x;
  const float* W = (layer == 0) ? W0 : (layer == 1) ? W1 : W2;
  int j = i & 7, lane = (i >> 3) & 63, ks = (i >> 9) & 3, nt = i >> 11;
  int k = ks * 32 + (lane >> 4) * 8 + j;
  int nn = nt * 16 + (lane & 15);
  float w = W[k * 128 + nn];
  unsigned short h = f2bf(w);
  float hf = __uint_as_float(((unsigned)h) << 16);
  Whi[layer * 16384 + i] = (short)h;
  Wlo[layer * 16384 + i] = (short)f2bf(w - hf);
}

// uber0: [count_deg(returning, writes rank) | wsplit(192) | graph_bounds
//         | pool-zero]
__global__ __launch_bounds__(256) void uber0_kernel(
    const int* __restrict__ dst, int* __restrict__ indeg, int* __restrict__ rank,
    int E,
    const float* __restrict__ W0, const float* __restrict__ W1,
    const float* __restrict__ W2, short* __restrict__ Whi, short* __restrict__ Wlo,
    const int* __restrict__ batch, int* __restrict__ gptr, int n, int G,
    float* __restrict__ pool, int CD, int GBD) {
  int b = blockIdx.x;
  if (b < CD) {
    int e = b * 256 + threadIdx.x;
    if (e < E) rank[e] = atomicAdd(&indeg[dst[e]], 1);
  } else if (b < CD + 192) {
    wsplit_body(b - CD, W0, W1, W2, Whi, Wlo);
  } else if (b < CD + 192 + GBD) {
    int i = (b - CD - 192) * 256 + threadIdx.x;
    if (i < n) {
      int bb = batch[i];
      if (i == 0) {
        for (int g = 0; g <= bb; ++g) gptr[g] = 0;
      } else {
        int bp = batch[i - 1];
        for (int g = bp + 1; g <= bb; ++g) gptr[g] = i;
      }
      if (i == n - 1) {
        for (int g = bb + 1; g <= G; ++g) gptr[g] = n;
      }
    }
  } else {
    int i = (b - CD - 192 - GBD) * 256 + threadIdx.x;
    if (i * 4 < G * 128) ((float4*)pool)[i] = make_float4(0.f, 0.f, 0.f, 0.f);
  }
}

// atomic-free CSR fill: pos = ptr[d] + rank[e]  (ptr table is L2-resident)
__global__ void fill_all_kernel(const int* __restrict__ src, const int* __restrict__ dst,
                                const int* __restrict__ rank, const int* __restrict__ ptr,
                                int* __restrict__ csrc, int E) {
  int i = blockIdx.x * 256 + threadIdx.x;
  if (i < E) {
    int s = src[i], d = dst[i], r = rank[i];
    csrc[ptr[d] + r] = s;
  }
}

// gemm1: H[n,128] = (X @ W + b) * rsq[row] via 3x bf16-split MFMA
__global__ __launch_bounds__(256) void gemm1_kernel(
    const float* __restrict__ X, const short* __restrict__ Whi,
    const short* __restrict__ Wlo, const float* __restrict__ bias,
    const float* __restrict__ rsq, float* __restrict__ H, int n) {
  int wave = threadIdx.x >> 6, lane = threadIdx.x & 63;
  int quad = lane >> 4, m = lane & 15;
  int mbase = blockIdx.x * 64 + wave * 16;
  int row = min(mbase + m, n - 1);
  const float* xr = X + (size_t)row * 128 + quad * 8;
  const s16x8* WH = (const s16x8*)Whi;
  const s16x8* WL = (const s16x8*)Wlo;
  f32x4 acc[8];
#pragma unroll
  for (int nt = 0; nt < 8; ++nt) acc[nt] = 0.f;
#pragma unroll
  for (int ks = 0; ks < 4; ++ks) {
    float4 xa = *(const float4*)(xr + ks * 32);
    float4 xb = *(const float4*)(xr + ks * 32 + 4);
    float xs[8] = {xa.x, xa.y, xa.z, xa.w, xb.x, xb.y, xb.z, xb.w};
    s16x8 ah, al;
#pragma unroll
    for (int j = 0; j < 8; ++j) {
      unsigned short h = f2bf(xs[j]);
      float hf = __uint_as_float(((unsigned)h) << 16);
      ah[j] = (short)h;
      al[j] = (short)f2bf(xs[j] - hf);
    }
#pragma unroll
    for (int nt = 0; nt < 8; ++nt) {
      s16x8 wh = WH[(nt * 4 + ks) * 64 + lane];
      s16x8 wl = WL[(nt * 4 + ks) * 64 + lane];
      acc[nt] = __builtin_amdgcn_mfma_f32_16x16x32_bf16(ah, wh, acc[nt], 0, 0, 0);
      acc[nt] = __builtin_amdgcn_mfma_f32_16x16x32_bf16(al, wh, acc[nt], 0, 0, 0);
      acc[nt] = __builtin_amdgcn_mfma_f32_16x16x32_bf16(ah, wl, acc[nt], 0, 0, 0);
    }
  }
  float rs[4];
#pragma unroll
  for (int r = 0; r < 4; ++r) {
    int rr = mbase + quad * 4 + r;
    rs[r] = (rr < n) ? rsq[rr] : 0.f;
  }
#pragma unroll
  for (int nt = 0; nt < 8; ++nt) {
    int col = nt * 16 + m;
    float b = bias[col];
#pragma unroll
    for (int r = 0; r < 4; ++r) {
      int rr = mbase + quad * 4 + r;
      if (rr < n) H[(size_t)rr * 128 + col] = (acc[nt][r] + b) * rs[r];
    }
  }
}

// Aggregate core: half-wave sums one node's gathered rows + own row (self).
// Guarded 8-deep unroll: up to 16 independent float4 gathers in flight/wave.
__device__ __forceinline__ f32x4 agg_sum(
    const f32x4* __restrict__ Hc, const int* __restrict__ ptr,
    const int* __restrict__ csrc, int node, int hl) {
  int beg = ptr[node], end = ptr[node + 1];
  f32x4 a0 = Hc[(size_t)node * 32];  // self-loop term (pre-scaled row)
  f32x4 a1 = 0.f, a2 = 0.f, a3 = 0.f;
  f32x4 a4 = 0.f, a5 = 0.f, a6 = 0.f, a7 = 0.f;
  for (int base = beg; base < end; base += 32) {
    int m = end - base;
    if (m > 32) m = 32;
    int sl = (hl < m) ? csrc[base + hl] : 0;
    int j = 0;
    for (; j + 7 < m; j += 8) {
      int s0 = __shfl(sl, j + 0, 32), s1 = __shfl(sl, j + 1, 32);
      int s2 = __shfl(sl, j + 2, 32), s3 = __shfl(sl, j + 3, 32);
      int s4 = __shfl(sl, j + 4, 32), s5 = __shfl(sl, j + 5, 32);
      int s6 = __shfl(sl, j + 6, 32), s7 = __shfl(sl, j + 7, 32);
      f32x4 h0 = Hc[(size_t)s0 * 32];
      f32x4 h1 = Hc[(size_t)s1 * 32];
      f32x4 h2 = Hc[(size_t)s2 * 32];
      f32x4 h3 = Hc[(size_t)s3 * 32];
      f32x4 h4 = Hc[(size_t)s4 * 32];
      f32x4 h5 = Hc[(size_t)s5 * 32];
      f32x4 h6 = Hc[(size_t)s6 * 32];
      f32x4 h7 = Hc[(size_t)s7 * 32];
      a0 += h0; a1 += h1; a2 += h2; a3 += h3;
      a4 += h4; a5 += h5; a6 += h6; a7 += h7;
    }
    for (; j + 3 < m; j += 4) {
      int s0 = __shfl(sl, j + 0, 32), s1 = __shfl(sl, j + 1, 32);
      int s2 = __shfl(sl, j + 2, 32), s3 = __shfl(sl, j + 3, 32);
      f32x4 h0 = Hc[(size_t)s0 * 32];
      f32x4 h1 = Hc[(size_t)s1 * 32];
      f32x4 h2 = Hc[(size_t)s2 * 32];
      f32x4 h3 = Hc[(size_t)s3 * 32];
      a0 += h0; a1 += h1; a2 += h2; a3 += h3;
    }
    for (; j < m; ++j) {
      int s0 = __shfl(sl, j, 32);
      a0 += Hc[(size_t)s0 * 32];
    }
  }
  return ((a0 + a1) + (a2 + a3)) + ((a4 + a5) + (a6 + a7));
}

// FUSED aggregate + next-layer GEMM (layers 2 and 3); epilogue scales by rsq.
#define LDS_STRIDE 132
__global__ __launch_bounds__(256) void agg_gemm_kernel(
    const float* __restrict__ H, const int* __restrict__ ptr,
    const int* __restrict__ csrc, const float* __restrict__ rsq,
    const short* __restrict__ Whi, const short* __restrict__ Wlo,
    const float* __restrict__ bias, float* __restrict__ Hout, int n) {
  __shared__ int lds[16 * LDS_STRIDE];
  int hw = threadIdx.x >> 5, hl = threadIdx.x & 31;
  int nbase = blockIdx.x * 16;
  const f32x4* Hc = (const f32x4*)(H + hl * 4);
#pragma unroll
  for (int rep = 0; rep < 2; ++rep) {
    int nl = hw + rep * 8;
    int node = nbase + nl;
    f32x4 o = 0.f;
    if (node < n) {
      f32x4 s = agg_sum(Hc, ptr, csrc, node, hl);
      float r = rsq[node];
      o.x = fmaxf(s.x * r, 0.f);
      o.y = fmaxf(s.y * r, 0.f);
      o.z = fmaxf(s.z * r, 0.f);
      o.w = fmaxf(s.w * r, 0.f);
    }
    int* dst = lds + nl * LDS_STRIDE + hl * 4;
#pragma unroll
    for (int c = 0; c < 4; ++c) {
      float v = o[c];
      unsigned short h = f2bf(v);
      float hf = __uint_as_float(((unsigned)h) << 16);
      unsigned short l = f2bf(v - hf);
      dst[c] = (int)((((unsigned)h) << 16) | l);
    }
  }
  __syncthreads();

  int wave = threadIdx.x >> 6, lane = threadIdx.x & 63;
  int quad = lane >> 4, m = lane & 15;
  const s16x8* WH = (const s16x8*)Whi;
  const s16x8* WL = (const s16x8*)Wlo;
  f32x4 acc0 = 0.f, acc1 = 0.f;
  int nt0 = wave * 2, nt1 = wave * 2 + 1;
#pragma unroll
  for (int ks = 0; ks < 4; ++ks) {
    const int* arow = lds + m * LDS_STRIDE + ks * 32 + quad * 8;
    s16x8 ah, al;
#pragma unroll
    for (int j = 0; j < 8; ++j) {
      unsigned p = (unsigned)arow[j];
      ah[j] = (short)(p >> 16);
      al[j] = (short)(p & 0xffffu);
    }
    s16x8 wh0 = WH[(nt0 * 4 + ks) * 64 + lane];
    s16x8 wl0 = WL[(nt0 * 4 + ks) * 64 + lane];
    s16x8 wh1 = WH[(nt1 * 4 + ks) * 64 + lane];
    s16x8 wl1 = WL[(nt1 * 4 + ks) * 64 + lane];
    acc0 = __builtin_amdgcn_mfma_f32_16x16x32_bf16(ah, wh0, acc0, 0, 0, 0);
    acc0 = __builtin_amdgcn_mfma_f32_16x16x32_bf16(al, wh0, acc0, 0, 0, 0);
    acc0 = __builtin_amdgcn_mfma_f32_16x16x32_bf16(ah, wl0, acc0, 0, 0, 0);
    acc1 = __builtin_amdgcn_mfma_f32_16x16x32_bf16(ah, wh1, acc1, 0, 0, 0);
    acc1 = __builtin_amdgcn_mfma_f32_16x16x32_bf16(al, wh1, acc1, 0, 0, 0);
    acc1 = __builtin_amdgcn_mfma_f32_16x16x32_bf16(ah, wl1, acc1, 0, 0, 0);
  }
  float rs[4];
#pragma unroll
  for (int r = 0; r < 4; ++r) {
    int rr = nbase + quad * 4 + r;
    rs[r] = (rr < n) ? rsq[rr] : 0.f;
  }
#pragma unroll
  for (int t = 0; t < 2; ++t) {
    int nt = wave * 2 + t;
    int col = nt * 16 + m;
    float b = bias[col];
    f32x4 a = t ? acc1 : acc0;
#pragma unroll
    for (int r = 0; r < 4; ++r) {
      int rr = nbase + quad * 4 + r;
      if (rr < n) Hout[(size_t)rr * 128 + col] = (a[r] + b) * rs[r];
    }
  }
}

// FUSED layer-3 aggregate + segment-sum pool (block per-graph partials).
__global__ __launch_bounds__(256) void agg_pool_kernel(
    const float* __restrict__ H, const int* __restrict__ ptr,
    const int* __restrict__ csrc, const float* __restrict__ rsq,
    const int* __restrict__ batch, float* __restrict__ pool, int n) {
  __shared__ float rows[16][128];
  __shared__ int gids[16];
  int hw = threadIdx.x >> 5, hl = threadIdx.x & 31;
  int nbase = blockIdx.x * 16;
  const f32x4* Hc = (const f32x4*)(H + hl * 4);
#pragma unroll
  for (int rep = 0; rep < 2; ++rep) {
    int nl = hw + rep * 8;
    int node = nbase + nl;
    f32x4 o = 0.f;
    if (node < n) {
      f32x4 s = agg_sum(Hc, ptr, csrc, node, hl);
      float r = rsq[node];
      o.x = fmaxf(s.x * r, 0.f);
      o.y = fmaxf(s.y * r, 0.f);
      o.z = fmaxf(s.z * r, 0.f);
      o.w = fmaxf(s.w * r, 0.f);
    }
    *(f32x4*)&rows[nl][hl * 4] = o;
    if (hl == 0) gids[nl] = (node < n) ? batch[node] : -1;
  }
  __syncthreads();
  int half = threadIdx.x >> 7;
  int ch = threadIdx.x & 127;
  float acc = 0.f;
  int curg = gids[half * 8];
  for (int i = half * 8; i < half * 8 + 8; ++i) {
    int g = gids[i];
    if (g != curg) {
      if (curg >= 0) atomicAdd(&pool[(size_t)curg * 128 + ch], acc);
      acc = 0.f;
      curg = g;
    }
    if (g >= 0) acc += rows[i][ch];
  }
  if (curg >= 0) atomicAdd(&pool[(size_t)curg * 128 + ch], acc);
}

// MLP head per graph: mean = pool/cnt (cnt from gptr), 2-layer MLP.
__global__ __launch_bounds__(128) void head_kernel(
    const float* __restrict__ pool, const int* __restrict__ gptr,
    const float* __restrict__ Wp1, const float* __restrict__ bp1,
    const float* __restrict__ Wp2, const float* __restrict__ bp2,
    float* __restrict__ out, int G) {
  int g = blockIdx.x;
  int j = threadIdx.x;
  __shared__ float ps[128];
  __shared__ float hs[128];
  int cnt = gptr[g + 1] - gptr[g];
  float inv = 1.0f / (float)max(cnt, 1);
  ps[j] = pool[(size_t)g * 128 + j] * inv;
  __syncthreads();
  float acc = bp1[j];
#pragma unroll 8
  for (int k = 0; k < 128; ++k) acc = fmaf(ps[k], Wp1[k * 128 + j], acc);
  hs[j] = fmaxf(acc, 0.f) * Wp2[j];
  __syncthreads();
  for (int off = 64; off > 0; off >>= 1) {
    if (j < off) hs[j] += hs[j + off];
    __syncthreads();
  }
  if (j == 0) out[g] = hs[0] + bp2[0];
}

extern "C" void kernel_launch(void* const* d_in, const int* in_sizes, int n_in,
                              void* d_out, int out_size, void* d_ws, size_t ws_size,
                              hipStream_t stream) {
  const float* x    = (const float*)d_in[0];
  const int*   eidx = (const int*)d_in[1];
  const int*   batch= (const int*)d_in[2];
  const float* W0 = (const float*)d_in[3];
  const float* b0 = (const float*)d_in[4];
  const float* W1 = (const float*)d_in[5];
  const float* b1 = (const float*)d_in[6];
  const float* W2 = (const float*)d_in[7];
  const float* b2 = (const float*)d_in[8];
  const float* Wp1 = (const float*)d_in[9];
  const float* bp1 = (const float*)d_in[10];
  const float* Wp2 = (const float*)d_in[11];
  const float* bp2 = (const float*)d_in[12];
  float* out = (float*)d_out;

  const int N = in_sizes[0] / 128;
  const int E = in_sizes[1] / 2;
  const int G = out_size;
  const int T = (N + 1023) / 1024;

  const int* src = eidx;
  const int* dst = eidx + E;

  char* ws = (char*)d_ws;
  size_t off = 0;
  auto alloc = [&](size_t bytes) -> void* {
    void* p = ws + off;
    off = (off + bytes + 255) & ~(size_t)255;
    return p;
  };
  int*   indeg   = (int*)  alloc((size_t)N * 4);
  int*   ptr     = (int*)  alloc((size_t)(N + 1) * 4);
  float* rsq     = (float*)alloc((size_t)N * 4);
  int*   rank    = (int*)  alloc((size_t)E * 4);
  int*   csrc    = (int*)  alloc((size_t)E * 4);
  float* bufA    = (float*)alloc((size_t)N * 128 * 4);
  float* bufB    = (float*)alloc((size_t)N * 128 * 4);
  int*   gptr    = (int*)  alloc((size_t)(G + 1) * 4);
  float* pool    = (float*)alloc((size_t)G * 128 * 4);
  int*   tilesum = (int*)  alloc((size_t)T * 4);
  short* whi     = (short*)alloc(3 * 16384 * 2);
  short* wlo     = (short*)alloc(3 * 16384 * 2);
  (void)ws_size;

  hipMemsetAsync(indeg, 0, (size_t)N * 4, stream);

  const int CD  = (E + 255) / 256;
  const int GBD = (N + 255) / 256;
  const int PZ  = (G * 128 / 4 + 255) / 256;
  uber0_kernel<<<CD + 192 + GBD + PZ, 256, 0, stream>>>(
      dst, indeg, rank, E, W0, W1, W2, whi, wlo, batch, gptr, N, G, pool,
      CD, GBD);

  tile_reduce_kernel<<<T, 1024, 0, stream>>>(indeg, tilesum, N);
  scan_emit_kernel<<<T, 1024, 0, stream>>>(indeg, tilesum, ptr, rsq, N, T);

  fill_all_kernel<<<(E + 255) / 256, 256, 0, stream>>>(src, dst, rank, ptr, csrc, E);
  gemm1_kernel<<<(N + 63) / 64, 256, 0, stream>>>(x, whi, wlo, b0, rsq, bufA, N);

  dim3 fused_grid((N + 15) / 16);
  agg_gemm_kernel<<<fused_grid, 256, 0, stream>>>(bufA, ptr, csrc, rsq,
      whi + 16384, wlo + 16384, b1, bufB, N);
  agg_gemm_kernel<<<fused_grid, 256, 0, stream>>>(bufB, ptr, csrc, rsq,
      whi + 2 * 16384, wlo + 2 * 16384, b2, bufA, N);
  agg_pool_kernel<<<fused_grid, 256, 0, stream>>>(bufA, ptr, csrc, rsq, batch, pool, N);

  head_kernel<<<G, 128, 0, stream>>>(pool, gptr, Wp1, bp1, Wp2, bp2, out, G);
}